// Round 3
// baseline (430.528 us; speedup 1.0000x reference)
//
#include <hip/hip_runtime.h>
#include <hip/hip_bf16.h>
#include <stdint.h>

#define ALPHA 0.01f

typedef __attribute__((ext_vector_type(8))) short short8;
typedef __attribute__((ext_vector_type(4))) float f32x4;
typedef __attribute__((ext_vector_type(4))) float float4_;
typedef __attribute__((ext_vector_type(4))) unsigned short ushort4_;
typedef unsigned int u32;

// round-to-nearest-even f32 -> bf16 bit pattern
static __device__ __forceinline__ unsigned short f2bf(float f) {
    union { float f; u32 u; } v; v.f = f;
    u32 r = v.u + 0x7FFF + ((v.u >> 16) & 1);
    return (unsigned short)(r >> 16);
}

// async global->LDS, 16B per lane. LDS dest is wave-uniform base + lane*16.
static __device__ __forceinline__ void lds_load16(const void* g, void* l) {
    __builtin_amdgcn_global_load_lds((const __attribute__((address_space(1))) u32*)g,
                                     (__attribute__((address_space(3))) u32*)l, 16, 0, 0);
}

// ---------------------------------------------------------------------------
// Kernel 1 (merged preps): blocks 0..511 cast W1/W2 to bf16 transposed;
// blocks 512..515 compute u[v][d] = sum_n W[d][n]*a_half[n]
__global__ __launch_bounds__(256) void k_prep(const float* __restrict__ W1, const float* __restrict__ a1,
                                              const float* __restrict__ W2, const float* __restrict__ a2,
                                              unsigned short* __restrict__ W1T, unsigned short* __restrict__ W2T,
                                              float* __restrict__ u) {
    int bb = blockIdx.x;
    if (bb < 512) {
        const float* W = (bb & 256) ? W2 : W1;
        unsigned short* WT = (bb & 256) ? W2T : W1T;
        int n = bb & 255, k = threadIdx.x;
        WT[n * 256 + k] = f2bf(W[k * 256 + n]);
    } else {
        int v = bb - 512;
        const float* W = (v < 2) ? W1 : W2;
        const float* a = ((v < 2) ? a1 : a2) + (v & 1) * 256;
        int d = threadIdx.x;
        float acc = 0.f;
        for (int n = 0; n < 256; n++) acc += W[d * 256 + n] * a[n];
        u[v * 256 + d] = acc;
    }
}

// Kernel 2: cast inputs to bf16 + compute the 4 score GEMVs in fp32.
__global__ __launch_bounds__(256) void k_cast_s(const float* __restrict__ in1, const float* __restrict__ in2,
                                                const float* __restrict__ u,
                                                unsigned short* __restrict__ in1b, unsigned short* __restrict__ in2b,
                                                float* __restrict__ s) {
    int gid = blockIdx.x * 4 + (threadIdx.x >> 6);   // one wave per row
    int tensor = gid >> 14;
    int row = gid & 16383;
    int lane = threadIdx.x & 63;
    const float* in = tensor ? in2 : in1;
    unsigned short* outb = tensor ? in2b : in1b;
    const float* uA = u + (tensor ? 256 : 0);
    const float* uB = u + (tensor ? 512 : 768);
    float* sA = s + (tensor ? 1 : 0) * 16384;
    float* sB = s + (tensor ? 2 : 3) * 16384;

    float4_ v = *(const float4_*)(in + row * 256 + lane * 4);
    float4_ ua = *(const float4_*)(uA + lane * 4);
    float4_ ub = *(const float4_*)(uB + lane * 4);
    ushort4_ ob;
    ob.x = f2bf(v.x); ob.y = f2bf(v.y); ob.z = f2bf(v.z); ob.w = f2bf(v.w);
    *(ushort4_*)(outb + row * 256 + lane * 4) = ob;
    float accA = v.x * ua.x + v.y * ua.y + v.z * ua.z + v.w * ua.w;
    float accB = v.x * ub.x + v.y * ub.y + v.z * ub.z + v.w * ub.w;
    for (int off = 32; off; off >>= 1) {
        accA += __shfl_xor(accA, off, 64);
        accB += __shfl_xor(accB, off, 64);
    }
    if (lane == 0) { sA[row] = accA; sB[row] = accB; }
}

// ---------------------------------------------------------------------------
// Kernel 3: WhT = (W^T) @ (in^T) as bf16 MFMA GEMM, double-buffered prefetch.
__global__ __launch_bounds__(256) void k_gemm_whT(const unsigned short* __restrict__ W1T,
                                                  const unsigned short* __restrict__ W2T,
                                                  const unsigned short* __restrict__ in1b,
                                                  const unsigned short* __restrict__ in2b,
                                                  unsigned short* __restrict__ whT1,
                                                  unsigned short* __restrict__ whT2) {
    __shared__ __attribute__((aligned(16))) unsigned short sA[2][128 * 32];
    __shared__ __attribute__((aligned(16))) unsigned short sB[2][128 * 32];
    int c = blockIdx.x >> 8;
    int bid = blockIdx.x & 255;
    int mt = bid & 1, ntile = bid >> 1;
    const unsigned short* A = c ? W2T : W1T;
    const unsigned short* Bm = c ? in1b : in2b;
    unsigned short* outp = c ? whT2 : whT1;
    int t = threadIdx.x;
    int w = t >> 6, lane = t & 63, l15 = lane & 15, lq = lane >> 4;
    int wm = (w & 1) * 64, wn = (w >> 1) * 64;
    f32x4 acc[4][4] = {};
    const unsigned short* gA = A + (mt * 128 + (t >> 2)) * 256 + (t & 3) * 8;
    const unsigned short* gB = Bm + (ntile * 128 + (t >> 2)) * 256 + (t & 3) * 8;

    // prologue: stage K-tile 0 into buf 0
    lds_load16(gA, &sA[0][t * 8]);
    lds_load16(gA + 64 * 256, &sA[0][t * 8 + 2048]);
    lds_load16(gB, &sB[0][t * 8]);
    lds_load16(gB + 64 * 256, &sB[0][t * 8 + 2048]);

    for (int it = 0; it < 8; ++it) {
        int kn = ((it + 1) & 7) * 32;             // wrap -> dummy re-stage on last iter
        unsigned short* dA = (unsigned short*)sA[(it + 1) & 1];
        unsigned short* dB = (unsigned short*)sB[(it + 1) & 1];
        lds_load16(gA + kn, dA + t * 8);
        lds_load16(gA + kn + 64 * 256, dA + t * 8 + 2048);
        lds_load16(gB + kn, dB + t * 8);
        lds_load16(gB + kn + 64 * 256, dB + t * 8 + 2048);
        __builtin_amdgcn_sched_barrier(0);
        // previous-iteration's 4 loads retired; this iteration's 4 stay in flight
        asm volatile("s_waitcnt vmcnt(4)" ::: "memory");
        __builtin_amdgcn_s_barrier();

        const unsigned short* cA = sA[it & 1];
        const unsigned short* cB = sB[it & 1];
        short8 af[4], bfr[4];
#pragma unroll
        for (int m2 = 0; m2 < 4; m2++) af[m2] = *(const short8*)&cA[(wm + m2 * 16 + l15) * 32 + lq * 8];
#pragma unroll
        for (int n2 = 0; n2 < 4; n2++) bfr[n2] = *(const short8*)&cB[(wn + n2 * 16 + l15) * 32 + lq * 8];
        __builtin_amdgcn_s_setprio(1);
#pragma unroll
        for (int m2 = 0; m2 < 4; m2++)
#pragma unroll
            for (int n2 = 0; n2 < 4; n2++)
                acc[m2][n2] = __builtin_amdgcn_mfma_f32_16x16x32_bf16(af[m2], bfr[n2], acc[m2][n2], 0, 0, 0);
        __builtin_amdgcn_s_setprio(0);
        asm volatile("s_waitcnt lgkmcnt(0)" ::: "memory");
        __builtin_amdgcn_s_barrier();
    }
#pragma unroll
    for (int m2 = 0; m2 < 4; m2++) {
#pragma unroll
        for (int n2 = 0; n2 < 4; n2++) {
            int i_glob = ntile * 128 + wn + n2 * 16 + l15;
            int bb = i_glob >> 11, ii = i_glob & 2047;
#pragma unroll
            for (int r = 0; r < 4; r++) {
                int d = mt * 128 + wm + m2 * 16 + lq * 4 + r;
                outp[bb * (256 * 2048) + d * 2048 + ii] = f2bf(acc[m2][n2][r]);
            }
        }
    }
}

// ---------------------------------------------------------------------------
// Kernel 4: fused stats + probs + ctx = P @ V.
// grid 512 = 2a x 8b x 32rg (XCD-clustered), 512 threads = 8 waves; wave w owns
// d-columns [w*32, w*32+32) for ALL 64 query rows -> no duplicated V reads.
// V is read DIRECTLY from global (L2-resident per XCD, 1MB panel) - no LDS staging.
// One barrier per 64-key iteration via double-buffered sP.
__global__ __launch_bounds__(512, 4) void k_attn(const float* __restrict__ s,
                                                 const unsigned short* __restrict__ whT1,
                                                 const unsigned short* __restrict__ whT2,
                                                 const float* __restrict__ mask1, const float* __restrict__ mask2,
                                                 float* __restrict__ out) {
    __shared__ __attribute__((aligned(16))) unsigned short sP[2][64 * 72];  // 64 rows x 64 cols, stride 72
    __shared__ float lsk2[2048];   // key scores * log2(e)
    __shared__ float lmk2[2048];   // mask * log2(e)
    __shared__ float lsq[64], lmx[64], lil[64];
    __shared__ float red[16];

    // bijective XCD swizzle: 64 consecutive lb per XCD = 2 full (a,b) panels -> V L2-resident
    int lb = (blockIdx.x & 7) * 64 + (blockIdx.x >> 3);
    int a = lb >> 8, b = (lb >> 5) & 7, rg = lb & 31;
    int t = threadIdx.x;
    const float* skp = s + (a ? 3 : 1) * 16384 + b * 2048;
    const float* sqp = s + (a ? 2 : 0) * 16384 + b * 2048 + rg * 64;
    const float* mp = (a ? mask1 : mask2) + b * 2048;
    const unsigned short* V = (a ? whT2 : whT1) + b * (256 * 2048);
    float* pout = out + 8388608 + a * 33554432 + (b * 2048 + rg * 64) * 2048;
    float* cout = out + a * 4194304 + (b * 2048 + rg * 64) * 256;

    const float L2E = 1.44269504f;
    // stage keys + mask in log2 domain, tracking maxes for the softmax shift
    float kmax = -3.4e38f, mmax = -3.4e38f;
    for (int j = t; j < 2048; j += 512) {
        float kv = skp[j] * L2E, mv = mp[j] * L2E;
        lsk2[j] = kv; lmk2[j] = mv;
        kmax = fmaxf(kmax, kv); mmax = fmaxf(mmax, mv);
    }
    if (t < 64) lsq[t] = sqp[t] * L2E;
    int w = t >> 6, lane = t & 63;
    for (int off = 32; off; off >>= 1) {
        kmax = fmaxf(kmax, __shfl_xor(kmax, off, 64));
        mmax = fmaxf(mmax, __shfl_xor(mmax, off, 64));
    }
    if (lane == 0) { red[w] = kmax; red[8 + w] = mmax; }
    __syncthreads();
    float skmax = fmaxf(fmaxf(fmaxf(red[0], red[1]), fmaxf(red[2], red[3])),
                        fmaxf(fmaxf(red[4], red[5]), fmaxf(red[6], red[7])));
    float mkmax = fmaxf(fmaxf(fmaxf(red[8], red[9]), fmaxf(red[10], red[11])),
                        fmaxf(fmaxf(red[12], red[13]), fmaxf(red[14], red[15])));

    // single sum pass per row; shift m = lrelu(sq + max sk) + max mk >= max_j x (monotonicity)
    // lrelu(y)+c folded: max(y,.01y)+c = max(y+c, .01y+c); per-row consts sqc, sq01
    for (int rr = 0; rr < 8; rr++) {
        int row = w * 8 + rr;
        float sqL2 = lsq[row];
        float yM = sqL2 + skmax;
        float mL2 = fmaxf(yM, yM * ALPHA) + mkmax;
        float cc = -mL2;
        float sqc = sqL2 + cc;
        float sq01 = __builtin_fmaf(ALPHA, sqL2, cc);
        float sum = 0.f;
        for (int j = lane; j < 2048; j += 64) {
            float k2 = lsk2[j];
            float e = fmaxf(sqc + k2, __builtin_fmaf(ALPHA, k2, sq01)) + lmk2[j];
            sum += exp2f(e);
        }
        for (int off = 32; off; off >>= 1) sum += __shfl_xor(sum, off, 64);
        if (lane == 0) { lmx[row] = mL2; lil[row] = 1.0f / sum; }
    }
    __syncthreads();

    int l15 = lane & 15, lq = lane >> 4;
    f32x4 acc[4][2] = {};
    int pi = t >> 3, pjq = t & 7;               // P row / 8-col group this thread computes
    float sqL2 = lsq[pi], ilv = lil[pi];
    float cc = -lmx[pi];
    float sqc = sqL2 + cc;
    float sq01 = __builtin_fmaf(ALPHA, sqL2, cc);
    const float* kkp = lsk2 + pjq * 8;
    const float* mmp = lmk2 + pjq * 8;
    float* gp = pout + pi * 2048 + pjq * 8;
    // per-lane V base: rows w*32 + n2*16 + l15, k-cols lq*8
    const unsigned short* gV = V + (w * 32 + l15) * 2048 + lq * 8;

    for (int it = 0; it < 32; ++it) {
        int j0 = it * 64;
        // V fragments for THIS iter, direct from global (L2-hit); latency hides under probs phase
        short8 bfr[2][2];
#pragma unroll
        for (int n2 = 0; n2 < 2; n2++)
#pragma unroll
            for (int ks = 0; ks < 2; ks++)
                bfr[n2][ks] = *(const short8*)(gV + n2 * (16 * 2048) + j0 + ks * 32);

        // probs phase: 8 elements/thread (row pi, cols j0+pjq*8 ..+7)
        float pv[8];
#pragma unroll
        for (int q = 0; q < 8; q++) {
            float k2 = kkp[j0 + q];
            float e = fmaxf(sqc + k2, __builtin_fmaf(ALPHA, k2, sq01)) + mmp[j0 + q];
            pv[q] = exp2f(e) * ilv;
        }
        float4_ v0, v1;
        v0.x = pv[0]; v0.y = pv[1]; v0.z = pv[2]; v0.w = pv[3];
        v1.x = pv[4]; v1.y = pv[5]; v1.z = pv[6]; v1.w = pv[7];
        __builtin_nontemporal_store(v0, (float4_*)(gp + j0));
        __builtin_nontemporal_store(v1, (float4_*)(gp + j0) + 1);
        union { short8 v; unsigned short us[8]; } pk;
#pragma unroll
        for (int q = 0; q < 8; q++) pk.us[q] = f2bf(pv[q]);
        *(short8*)&sP[it & 1][pi * 72 + pjq * 8] = pk.v;

        // single barrier: sP[it&1] visible. No vmcnt wait anywhere in the loop.
        asm volatile("s_waitcnt lgkmcnt(0)" ::: "memory");
        __builtin_amdgcn_s_barrier();
        __builtin_amdgcn_sched_barrier(0);

        const unsigned short* sp = sP[it & 1];
        __builtin_amdgcn_s_setprio(1);
#pragma unroll
        for (int ks = 0; ks < 2; ks++)
#pragma unroll
            for (int m2 = 0; m2 < 4; m2++) {
                short8 af = *(const short8*)&sp[(m2 * 16 + l15) * 72 + ks * 32 + lq * 8];
#pragma unroll
                for (int n2 = 0; n2 < 2; n2++)
                    acc[m2][n2] = __builtin_amdgcn_mfma_f32_16x16x32_bf16(af, bfr[n2][ks], acc[m2][n2], 0, 0, 0);
            }
        __builtin_amdgcn_s_setprio(0);
        // no second barrier: next iter writes the OTHER sP buffer; this iter's reads
        // complete before their uses, which precede the next barrier in program order.
    }

    // ctx epilogue: D[m=i][n=d]; i = m2*16 + lq*4 + r, d = w*32 + n2*16 + l15
#pragma unroll
    for (int m2 = 0; m2 < 4; m2++) {
#pragma unroll
        for (int n2 = 0; n2 < 2; n2++) {
#pragma unroll
            for (int r = 0; r < 4; r++) {
                int i_loc = m2 * 16 + lq * 4 + r;
                int d_loc = w * 32 + n2 * 16 + l15;
                __builtin_nontemporal_store(acc[m2][n2][r], cout + i_loc * 256 + d_loc);
            }
        }
    }
}

// ---------------------------------------------------------------------------
extern "C" void kernel_launch(void* const* d_in, const int* in_sizes, int n_in,
                              void* d_out, int out_size, void* d_ws, size_t ws_size,
                              hipStream_t stream) {
    const float* in1   = (const float*)d_in[0];
    const float* mask1 = (const float*)d_in[1];
    const float* in2   = (const float*)d_in[2];
    const float* mask2 = (const float*)d_in[3];
    const float* W1    = (const float*)d_in[4];
    const float* a1    = (const float*)d_in[5];
    const float* W2    = (const float*)d_in[6];
    const float* a2    = (const float*)d_in[7];
    float* out = (float*)d_out;
    char* ws = (char*)d_ws;

    unsigned short* in1b = (unsigned short*)(ws);
    unsigned short* in2b = (unsigned short*)(ws + 8388608);
    unsigned short* whT1 = (unsigned short*)(ws + 16777216);
    unsigned short* whT2 = (unsigned short*)(ws + 25165824);
    unsigned short* W1T  = (unsigned short*)(ws + 33554432);
    unsigned short* W2T  = (unsigned short*)(ws + 33685504);
    float* u    = (float*)(ws + 33816576);
    float* s    = (float*)(ws + 33820672);

    k_prep<<<516, 256, 0, stream>>>(W1, a1, W2, a2, W1T, W2T, u);
    k_cast_s<<<8192, 256, 0, stream>>>(in1, in2, u, in1b, in2b, s);
    k_gemm_whT<<<512, 256, 0, stream>>>(W1T, W2T, in1b, in2b, whT1, whT2);
    k_attn<<<512, 512, 0, stream>>>(s, whT1, whT2, mask1, mask2, out);
}